// Round 1
// baseline (268.198 us; speedup 1.0000x reference)
//
#include <hip/hip_runtime.h>

// x: (8, 320, 128, 128) fp32.  C=320 ≡ 0 mod 5  =>  plane%5 == channel%5.
// out(i,j) = (silu(x[s1]) + x[i,j]) * (sigmoid(silu(x[s2])) - 0.5)
// t=c%5: 0: s1=(i,j+1), s2=(i,j+2)   (mod 128)
//        1: s1=(i,j-1), s2=(i,j-2)
//        2: s1=(i+1,j), s2=(i+2,j)
//        3: s1=(i-1,j), s2=(i-2,j)
//        4: s1=s2=(i,j)

#define PLANE_ELEMS 16384   // 128*128
#define ROW_W 128

__device__ __forceinline__ float fast_sig(float z) {
    // 1/(1+exp(-z)) with native exp + native rcp; threshold is 0.103 absmax.
    return __builtin_amdgcn_rcpf(1.0f + __expf(-z));
}
__device__ __forceinline__ float fast_silu(float z) {
    return z * fast_sig(z);
}

__global__ __launch_bounds__(256) void ablock_kernel(const float* __restrict__ x,
                                                     float* __restrict__ out,
                                                     int nv4) {
    int g = blockIdx.x * blockDim.x + threadIdx.x;   // float4 index
    if (g >= nv4) return;

    int plane = g >> 12;          // 4096 float4 per 128x128 plane
    int o     = g & 4095;         // float4 offset within plane
    int row   = o >> 5;           // 32 float4 per row
    int c4    = o & 31;           // float4 index within row
    int col   = c4 << 2;          // starting column of this float4
    int t     = plane % 5;        // wave-uniform (wave spans 64 consec float4 < 4096)

    const float*  p  = x + (size_t)plane * PLANE_ELEMS;
    const float4* p4 = (const float4*)p;
    int rowbase = row << 7;

    float4 x0 = p4[o];
    float4 x1, x2;

    if (t == 0) {            // shift +1/+2 along W (circular)
        float e4 = p[rowbase + ((col + 4) & 127)];
        float e5 = p[rowbase + ((col + 5) & 127)];
        x1 = make_float4(x0.y, x0.z, x0.w, e4);
        x2 = make_float4(x0.z, x0.w, e4, e5);
    } else if (t == 1) {     // shift -1/-2 along W
        float em1 = p[rowbase + ((col - 1) & 127)];
        float em2 = p[rowbase + ((col - 2) & 127)];
        x1 = make_float4(em1, x0.x, x0.y, x0.z);
        x2 = make_float4(em2, em1, x0.x, x0.y);
    } else if (t == 2) {     // shift +1/+2 along H
        x1 = p4[(((row + 1) & 127) << 5) + c4];
        x2 = p4[(((row + 2) & 127) << 5) + c4];
    } else if (t == 3) {     // shift -1/-2 along H
        x1 = p4[(((row - 1) & 127) << 5) + c4];
        x2 = p4[(((row - 2) & 127) << 5) + c4];
    } else {                 // identity
        x1 = x0;
        x2 = x0;
    }

    float4 r;
    r.x = (fast_silu(x1.x) + x0.x) * (fast_sig(fast_silu(x2.x)) - 0.5f);
    r.y = (fast_silu(x1.y) + x0.y) * (fast_sig(fast_silu(x2.y)) - 0.5f);
    r.z = (fast_silu(x1.z) + x0.z) * (fast_sig(fast_silu(x2.z)) - 0.5f);
    r.w = (fast_silu(x1.w) + x0.w) * (fast_sig(fast_silu(x2.w)) - 0.5f);

    ((float4*)out)[g] = r;
}

extern "C" void kernel_launch(void* const* d_in, const int* in_sizes, int n_in,
                              void* d_out, int out_size, void* d_ws, size_t ws_size,
                              hipStream_t stream) {
    const float* x   = (const float*)d_in[0];
    float*       out = (float*)d_out;
    int n   = in_sizes[0];        // 41,943,040
    int nv4 = n >> 2;             // 10,485,760 float4
    int block = 256;
    int grid  = (nv4 + block - 1) / block;   // 40,960
    ablock_kernel<<<grid, block, 0, stream>>>(x, out, nv4);
}